// Round 2
// baseline (161.110 us; speedup 1.0000x reference)
//
#include <hip/hip_runtime.h>

#define B_ 8
#define T_ 2048
#define C_ 1024
#define H_ 64

typedef __attribute__((ext_vector_type(8))) short short8;
typedef __attribute__((ext_vector_type(4))) float floatx4;
typedef __attribute__((ext_vector_type(4))) int intx4;

static __device__ __forceinline__ unsigned short f2bf(float f) {
  unsigned int u = __builtin_bit_cast(unsigned int, f);
  u += 0x7FFFu + ((u >> 16) & 1u);   // RNE
  return (unsigned short)(u >> 16);
}
static __device__ __forceinline__ unsigned short f2bf_t(float f) {   // truncate
  return (unsigned short)(__builtin_bit_cast(unsigned int, f) >> 16);
}
static __device__ __forceinline__ float bf2f(unsigned short u) {
  return __builtin_bit_cast(float, ((unsigned int)u) << 16);
}
static __device__ __forceinline__ unsigned int fbits(float f) {
  return __builtin_bit_cast(unsigned int, f);
}

typedef const __attribute__((address_space(1))) unsigned int* gp1_t;
typedef __attribute__((address_space(3))) unsigned int* lp3_t;
static __device__ __forceinline__ void gl_lds16(const void* g, void* l) {
  __builtin_amdgcn_global_load_lds((gp1_t)g, (lp3_t)l, 16, 0, 0);
}

// ---------------------------------------------------------------------------
// Kernel 0: W fp32 -> Wf FRAGMENT-READY bf16 (unchanged).
// ---------------------------------------------------------------------------
__global__ __launch_bounds__(256) void conv_w(const float* __restrict__ wq,
    const float* __restrict__ wk, const float* __restrict__ wv,
    unsigned short* __restrict__ wf) {
  int c = blockIdx.x * 256 + threadIdx.x;   // 24576 chunks
  int lane = c & 63;
  int t = c >> 6;
  int ng = t % 12;
  int kk = t / 12;                           // kt*2+ks, 0..31
  int k0 = kk * 32 + (lane >> 4) * 8;
  int n = ng * 16 + (lane & 15);
  const float* src;
  int col;
  float scale = 1.0f;
  if (n < 64)       { src = wq; col = n;       scale = 0.03125f * 1.44269504088896340736f; }
  else if (n < 128) { src = wk; col = n - 64;  }
  else              { src = wv; col = n - 128; }
  unsigned short o[8];
#pragma unroll
  for (int j = 0; j < 8; ++j) o[j] = f2bf(src[(size_t)(k0 + j) * H_ + col] * scale);
  *(uint4*)&wf[(size_t)c * 8] = *(const uint4*)o;
}

// ---------------------------------------------------------------------------
// Kernel 1: QKV projection (unchanged this round; isolating the attn change).
// ---------------------------------------------------------------------------
__global__ __launch_bounds__(256, 4) void qkv_proj(
    const float* __restrict__ x, const unsigned short* __restrict__ wf,
    unsigned short* __restrict__ qo, unsigned short* __restrict__ kf,
    unsigned short* __restrict__ vf) {
  __shared__ float XL[2][4096];   // 2 x (32 rows x 128 fp32) = 32 KB
  int tid = threadIdx.x;
  int wave = tid >> 6, lane = tid & 63;
  int lane4 = lane & 15, quad = lane >> 4;
  int m0 = blockIdx.x * 32;
  int ph0 = blockIdx.x & 7;       // per-block K-order rotation

  // stage one phase (32 rows x 128 floats = 1024 16B-chunks, 4 insts/thread)
  auto stage_ph = [&](int phr, int buf) {
#pragma unroll
    for (int j = 0; j < 4; ++j) {
      int c = (wave * 4 + j) * 64 + lane;    // chunk id 0..1023
      int r = c >> 5, pc = c & 31;           // 32 chunks per row
      int cl = (pc & ~7) | ((pc ^ (r & 7)) & 7);
      gl_lds16(&x[(size_t)(m0 + r) * C_ + phr * 128 + cl * 4], &XL[buf][c * 4]);
    }
  };

  floatx4 acc[2][3];
#pragma unroll
  for (int mt = 0; mt < 2; ++mt)
#pragma unroll
    for (int nt = 0; nt < 3; ++nt) acc[mt][nt] = (floatx4)0.0f;

  stage_ph(ph0, 0);
  __syncthreads();

  for (int ph = 0; ph < 8; ++ph) {
    int buf = ph & 1;
    if (ph < 7) stage_ph((ph + 1 + ph0) & 7, buf ^ 1);   // async prefetch
    int phr = (ph + ph0) & 7;
#pragma unroll
    for (int sl = 0; sl < 4; ++sl) {
      int s = phr * 4 + sl;            // global ks-step, 0..31
      short8 b[3];
#pragma unroll
      for (int nt = 0; nt < 3; ++nt)
        b[nt] = *(const short8*)&wf[(size_t)(s * 12 + wave * 3 + nt) * 512 + lane * 8];
      short8 a[2];
#pragma unroll
      for (int mt = 0; mt < 2; ++mt) {
        int r = mt * 16 + lane4;
        int c0 = sl * 8 + quad * 2;    // phase-local float4-chunk, 0..31
        int pc0 = (c0 & ~7) | ((c0 ^ (r & 7)) & 7);
        int pc1 = ((c0 + 1) & ~7) | (((c0 + 1) ^ (r & 7)) & 7);
        float4 f0 = *(const float4*)&XL[buf][r * 128 + pc0 * 4];
        float4 f1 = *(const float4*)&XL[buf][r * 128 + pc1 * 4];
        intx4 pk;
        pk[0] = (int)__builtin_amdgcn_perm(fbits(f0.y), fbits(f0.x), 0x07060302u);
        pk[1] = (int)__builtin_amdgcn_perm(fbits(f0.w), fbits(f0.z), 0x07060302u);
        pk[2] = (int)__builtin_amdgcn_perm(fbits(f1.y), fbits(f1.x), 0x07060302u);
        pk[3] = (int)__builtin_amdgcn_perm(fbits(f1.w), fbits(f1.z), 0x07060302u);
        a[mt] = __builtin_bit_cast(short8, pk);
      }
#pragma unroll
      for (int mt = 0; mt < 2; ++mt)
#pragma unroll
        for (int nt = 0; nt < 3; ++nt)
          acc[mt][nt] = __builtin_amdgcn_mfma_f32_16x16x32_bf16(a[mt], b[nt], acc[mt][nt], 0, 0, 0);
    }
    __syncthreads();   // prefetch landed + all waves done with buf
  }

  // ---- epilogue: q direct; K,V via LDS into fragment-ready layouts ----
  unsigned short* VTB = (unsigned short*)&XL[0][0];   // [64 h][40] bf16 (V^T)
  unsigned short* KB  = VTB + 5120;                   // [32 t][72] bf16
#pragma unroll
  for (int mt = 0; mt < 2; ++mt)
#pragma unroll
    for (int nt = 0; nt < 3; ++nt) {
      int n = wave * 48 + nt * 16 + lane4;
#pragma unroll
      for (int rr = 0; rr < 4; ++rr) {
        unsigned short val = f2bf(acc[mt][nt][rr]);
        int lrow = mt * 16 + quad * 4 + rr;
        if (n < 64)       qo[(size_t)(m0 + lrow) * H_ + n] = val;
        else if (n < 128) KB[lrow * 72 + (n - 64)] = val;
        else              VTB[(n - 128) * 40 + lrow] = val;
      }
    }
  __syncthreads();
  {
    int bb = m0 >> 11, t0 = m0 & 2047;
    int st = t0 >> 6, off = t0 & 63;
    // K: 256 chunks (ks x ctl x 64 lanes)
    int ks = tid >> 7, ctl = (tid >> 6) & 1, ln = tid & 63;
    int ct = (off >> 4) + ctl;
    int tl = ctl * 16 + (ln & 15);
    int h0 = ks * 32 + (ln >> 4) * 8;
    uint4 kd = *(const uint4*)&KB[tl * 72 + h0];
    *(uint4*)&kf[((size_t)((bb * 32 + st) * 2 + ks) * 4 + ct) * 512 + ln * 8] = kd;
    // V: 256 chunks (nt x 64 lanes), ks fixed = off>>5
    int nt = tid >> 6, l4 = tid & 15, qs = (tid >> 4) & 3;
    int ksv = off >> 5;
    uint4 vd = *(const uint4*)&VTB[(nt * 16 + l4) * 40 + qs * 8];
    *(uint4*)&vf[((size_t)((bb * 32 + st) * 2 + ksv) * 4 + nt) * 512 + (tid & 63) * 8] = vd;
  }
}

// ---------------------------------------------------------------------------
// Kernel 2: causal flash attention, split-4, fixed-max softmax.
// R15 CHANGE (chain-ILP): R14's neutral result says data movement wasn't the
// attn cost; the per-tile SERIAL chain (ds_read -> QK -> exp -> PL roundtrip
// -> PV -> barrier, ~1000cy) likely is. Now k-tiles are processed in PAIRS:
// two independent QK->softmax->PV chains in flight per iteration (separate
// PL regions), so tile t+1's MFMA/exp/LDS ops fill tile t's latency bubbles.
// Barriers halved (2 per pair, not 2 per tile). Prefetch = T14 reg-staging
// (issue next pair's global loads before compute; ds_write after the
// read-barrier) -- keeps LDS at 50 KB (2x16 KB KV halves + 2x9 KB PL) ->
// 3 blocks/CU, while a gl_lds double-buffer of a 2-tile set would be 82 KB.
// s_setprio(1) wraps the MFMA clusters (T5, +4-7% on attn-like structures).
// ---------------------------------------------------------------------------
__global__ __launch_bounds__(256, 3) void attn(
    const unsigned short* __restrict__ qi, const unsigned short* __restrict__ Kf,
    const unsigned short* __restrict__ Vf, unsigned short* __restrict__ Op,
    float* __restrict__ lsum) {
  __shared__ unsigned short KVS[2][8192];   // [half][ K: 0..4095 | V: 4096..8191 ]
  __shared__ unsigned short PL[2][4][16][72];

  int tid = threadIdx.x;
  int wave = tid >> 6, lane = tid & 63;
  int lane4 = lane & 15, quad = lane >> 4;
  int qt = 31 - (int)blockIdx.x;   // biggest blocks dispatch first
  int b = blockIdx.y, split = blockIdx.z;
  int qb = qt * 64;
  int base = b * T_;

  int ntile = qt + 1;
  int sBeg = (split * ntile) >> 2;
  int sEnd = ((split + 1) * ntile) >> 2;

  short8 aq[2];
#pragma unroll
  for (int ks = 0; ks < 2; ++ks)
    aq[ks] = *(const short8*)&qi[(size_t)(base + qb + wave * 16 + lane4) * H_ + ks * 32 + quad * 8];

  float lrow[4];
  floatx4 o[4];
#pragma unroll
  for (int r = 0; r < 4; ++r) lrow[r] = 0.0f;
#pragma unroll
  for (int nt = 0; nt < 4; ++nt) o[nt] = (floatx4)0.0f;

  // T14 reg-staging of a 2-tile pair: 2 x 16 KB / 256 thr = 8 x dwordx4.
  uint4 rs[8];
  auto stage_pair = [&](int t0) {      // issue global loads (guarded, uniform)
#pragma unroll
    for (int half = 0; half < 2; ++half) {
      int t = t0 + half;
      if (t < sEnd) {
#pragma unroll
        for (int j = 0; j < 4; ++j) {
          int c = j * 256 + tid;       // 16B-chunk 0..1023 of this tile
          const unsigned short* src = (c < 512)
              ? &Kf[(size_t)(b * 32 + t) * 4096 + c * 8]
              : &Vf[(size_t)(b * 32 + t) * 4096 + (size_t)(c - 512) * 8];
          rs[half * 4 + j] = *(const uint4*)src;
        }
      }
    }
  };
  auto write_pair = [&](int t0) {      // regs -> LDS (waits vmcnt via use)
#pragma unroll
    for (int half = 0; half < 2; ++half) {
      if (t0 + half < sEnd) {
#pragma unroll
        for (int j = 0; j < 4; ++j) {
          int c = j * 256 + tid;
          *(uint4*)&KVS[half][c * 8] = rs[half * 4 + j];
        }
      }
    }
  };

  auto tile_compute = [&](int st, int h, int pl) {
    floatx4 sacc[4];
#pragma unroll
    for (int ct = 0; ct < 4; ++ct) sacc[ct] = (floatx4)0.0f;
    __builtin_amdgcn_s_setprio(1);
#pragma unroll
    for (int ks = 0; ks < 2; ++ks)
#pragma unroll
      for (int ct = 0; ct < 4; ++ct) {
        short8 bk = *(const short8*)&KVS[h][(ks * 4 + ct) * 512 + lane * 8];
        sacc[ct] = __builtin_amdgcn_mfma_f32_16x16x32_bf16(aq[ks], bk, sacc[ct], 0, 0, 0);
      }
    __builtin_amdgcn_s_setprio(0);

    if (st == qt) {   // diagonal tile mask
#pragma unroll
      for (int ct = 0; ct < 4; ++ct)
#pragma unroll
        for (int r = 0; r < 4; ++r) {
          int qrow = wave * 16 + quad * 4 + r;
          int scol = ct * 16 + lane4;
          if (scol > qrow) sacc[ct][r] = -3.0e38f;
        }
    }

    // fixed-max softmax: p = exp2(s - 8)
#pragma unroll
    for (int ct = 0; ct < 4; ++ct)
#pragma unroll
      for (int r = 0; r < 4; ++r) {
        float p = exp2f(sacc[ct][r] - 8.0f);
        lrow[r] += p;
        PL[pl][wave][quad * 4 + r][ct * 16 + lane4] = f2bf_t(p);
      }

    // O += P V  (PL write->read same-wave; lgkmcnt orders it)
    __builtin_amdgcn_s_setprio(1);
#pragma unroll
    for (int ks = 0; ks < 2; ++ks) {
      short8 pa = *(const short8*)&PL[pl][wave][lane4][ks * 32 + quad * 8];
#pragma unroll
      for (int nt = 0; nt < 4; ++nt) {
        short8 bv = *(const short8*)&KVS[h][4096 + (ks * 4 + nt) * 512 + lane * 8];
        o[nt] = __builtin_amdgcn_mfma_f32_16x16x32_bf16(pa, bv, o[nt], 0, 0, 0);
      }
    }
    __builtin_amdgcn_s_setprio(0);
  };

  // prologue: stage + write pair (sBeg, sBeg+1)
  stage_pair(sBeg);
  write_pair(sBeg);
  __syncthreads();

  for (int st = sBeg; st < sEnd; st += 2) {
    stage_pair(st + 2);                 // issue next pair's loads early
    tile_compute(st, 0, 0);
    if (st + 1 < sEnd) tile_compute(st + 1, 1, 1);
    __syncthreads();                    // all waves done reading KVS halves
    write_pair(st + 2);
    __syncthreads();                    // next pair resident
  }

  // epilogue: l-reduce across the 16 lanes of each quad-group
#pragma unroll
  for (int off = 1; off < 16; off <<= 1)
#pragma unroll
    for (int r = 0; r < 4; ++r) lrow[r] += __shfl_xor(lrow[r], off);

  size_t pbase = (((size_t)split * 8 + b) * 32 + qt) * 64;
#pragma unroll
  for (int r = 0; r < 4; ++r) {
    int row = wave * 16 + quad * 4 + r;
#pragma unroll
    for (int nt = 0; nt < 4; ++nt)
      Op[(pbase + row) * 64 + nt * 16 + lane4] = f2bf(o[nt][r]);
    if (lane4 == 0) lsum[pbase + row] = lrow[r];
  }
}

// ---------------------------------------------------------------------------
// Kernel 3: merge the 4 key-range splits: out = sum(O_i) / sum(l_i).
// ---------------------------------------------------------------------------
__global__ __launch_bounds__(256) void merge_splits(
    const unsigned short* __restrict__ Op, const float* __restrict__ lsum,
    float* __restrict__ out) {
  int idx = blockIdx.x * 256 + threadIdx.x;
  int row = idx >> 4;
  int h4 = (idx & 15) * 4;
  int b = row >> 11, t = row & 2047;
  int qt = t >> 6, r = t & 63;
  float O0 = 0.f, O1 = 0.f, O2 = 0.f, O3 = 0.f, l = 0.f;
#pragma unroll
  for (int s = 0; s < 4; ++s) {
    size_t p = (((size_t)s * 8 + b) * 32 + qt) * 64 + r;
    l += lsum[p];
    ushort4 ov = *(const ushort4*)&Op[p * 64 + h4];
    O0 += bf2f(ov.x); O1 += bf2f(ov.y); O2 += bf2f(ov.z); O3 += bf2f(ov.w);
  }
  float inv = 1.0f / l;
  float4 res = make_float4(O0 * inv, O1 * inv, O2 * inv, O3 * inv);
  *(float4*)&out[(size_t)row * H_ + h4] = res;
}

extern "C" void kernel_launch(void* const* d_in, const int* in_sizes, int n_in,
                              void* d_out, int out_size, void* d_ws, size_t ws_size,
                              hipStream_t stream) {
  const float* x  = (const float*)d_in[0];
  const float* wq = (const float*)d_in[1];
  const float* wk = (const float*)d_in[2];
  const float* wv = (const float*)d_in[3];
  float* out = (float*)d_out;

  char* ws = (char*)d_ws;
  unsigned short* wf = (unsigned short*)ws;                    // 393216 B
  unsigned short* qb = (unsigned short*)(ws + 393216);         // 2097152 B
  unsigned short* kf = (unsigned short*)(ws + 2490368);        // 2097152 B (frag-ready)
  unsigned short* vf = (unsigned short*)(ws + 4587520);        // 2097152 B (frag-ready)
  unsigned short* Op = (unsigned short*)(ws + 6684672);        // 8388608 B (4 splits)
  float*          ls = (float*)(ws + 15073280);                // 262144 B (total 15335424)

  conv_w<<<96, 256, 0, stream>>>(wq, wk, wv, wf);
  qkv_proj<<<512, 256, 0, stream>>>(x, wf, qb, kf, vf);
  attn<<<dim3(32, 8, 4), 256, 0, stream>>>(qb, kf, vf, Op, ls);
  merge_splits<<<1024, 256, 0, stream>>>(Op, ls, out);
}

// Round 3
// 127.999 us; speedup vs baseline: 1.2587x; 1.2587x over previous
//
#include <hip/hip_runtime.h>

#define B_ 8
#define T_ 2048
#define C_ 1024
#define H_ 64

typedef __attribute__((ext_vector_type(8))) short short8;
typedef __attribute__((ext_vector_type(4))) float floatx4;
typedef __attribute__((ext_vector_type(4))) int intx4;

static __device__ __forceinline__ unsigned short f2bf(float f) {
  unsigned int u = __builtin_bit_cast(unsigned int, f);
  u += 0x7FFFu + ((u >> 16) & 1u);   // RNE
  return (unsigned short)(u >> 16);
}
static __device__ __forceinline__ unsigned short f2bf_t(float f) {   // truncate
  return (unsigned short)(__builtin_bit_cast(unsigned int, f) >> 16);
}
static __device__ __forceinline__ float bf2f(unsigned short u) {
  return __builtin_bit_cast(float, ((unsigned int)u) << 16);
}
static __device__ __forceinline__ unsigned int fbits(float f) {
  return __builtin_bit_cast(unsigned int, f);
}

typedef const __attribute__((address_space(1))) unsigned int* gp1_t;
typedef __attribute__((address_space(3))) unsigned int* lp3_t;
static __device__ __forceinline__ void gl_lds16(const void* g, void* l) {
  __builtin_amdgcn_global_load_lds((gp1_t)g, (lp3_t)l, 16, 0, 0);
}

// ---------------------------------------------------------------------------
// Kernel 0: W fp32 -> Wf FRAGMENT-READY bf16 (unchanged).
// ---------------------------------------------------------------------------
__global__ __launch_bounds__(256) void conv_w(const float* __restrict__ wq,
    const float* __restrict__ wk, const float* __restrict__ wv,
    unsigned short* __restrict__ wf) {
  int c = blockIdx.x * 256 + threadIdx.x;   // 24576 chunks
  int lane = c & 63;
  int t = c >> 6;
  int ng = t % 12;
  int kk = t / 12;                           // kt*2+ks, 0..31
  int k0 = kk * 32 + (lane >> 4) * 8;
  int n = ng * 16 + (lane & 15);
  const float* src;
  int col;
  float scale = 1.0f;
  if (n < 64)       { src = wq; col = n;       scale = 0.03125f * 1.44269504088896340736f; }
  else if (n < 128) { src = wk; col = n - 64;  }
  else              { src = wv; col = n - 128; }
  unsigned short o[8];
#pragma unroll
  for (int j = 0; j < 8; ++j) o[j] = f2bf(src[(size_t)(k0 + j) * H_ + col] * scale);
  *(uint4*)&wf[(size_t)c * 8] = *(const uint4*)o;
}

// ---------------------------------------------------------------------------
// Kernel 1: QKV projection (unchanged this round; isolating the attn change).
// ---------------------------------------------------------------------------
__global__ __launch_bounds__(256, 4) void qkv_proj(
    const float* __restrict__ x, const unsigned short* __restrict__ wf,
    unsigned short* __restrict__ qo, unsigned short* __restrict__ kf,
    unsigned short* __restrict__ vf) {
  __shared__ float XL[2][4096];   // 2 x (32 rows x 128 fp32) = 32 KB
  int tid = threadIdx.x;
  int wave = tid >> 6, lane = tid & 63;
  int lane4 = lane & 15, quad = lane >> 4;
  int m0 = blockIdx.x * 32;
  int ph0 = blockIdx.x & 7;       // per-block K-order rotation

  // stage one phase (32 rows x 128 floats = 1024 16B-chunks, 4 insts/thread)
  auto stage_ph = [&](int phr, int buf) {
#pragma unroll
    for (int j = 0; j < 4; ++j) {
      int c = (wave * 4 + j) * 64 + lane;    // chunk id 0..1023
      int r = c >> 5, pc = c & 31;           // 32 chunks per row
      int cl = (pc & ~7) | ((pc ^ (r & 7)) & 7);
      gl_lds16(&x[(size_t)(m0 + r) * C_ + phr * 128 + cl * 4], &XL[buf][c * 4]);
    }
  };

  floatx4 acc[2][3];
#pragma unroll
  for (int mt = 0; mt < 2; ++mt)
#pragma unroll
    for (int nt = 0; nt < 3; ++nt) acc[mt][nt] = (floatx4)0.0f;

  stage_ph(ph0, 0);
  __syncthreads();

  for (int ph = 0; ph < 8; ++ph) {
    int buf = ph & 1;
    if (ph < 7) stage_ph((ph + 1 + ph0) & 7, buf ^ 1);   // async prefetch
    int phr = (ph + ph0) & 7;
#pragma unroll
    for (int sl = 0; sl < 4; ++sl) {
      int s = phr * 4 + sl;            // global ks-step, 0..31
      short8 b[3];
#pragma unroll
      for (int nt = 0; nt < 3; ++nt)
        b[nt] = *(const short8*)&wf[(size_t)(s * 12 + wave * 3 + nt) * 512 + lane * 8];
      short8 a[2];
#pragma unroll
      for (int mt = 0; mt < 2; ++mt) {
        int r = mt * 16 + lane4;
        int c0 = sl * 8 + quad * 2;    // phase-local float4-chunk, 0..31
        int pc0 = (c0 & ~7) | ((c0 ^ (r & 7)) & 7);
        int pc1 = ((c0 + 1) & ~7) | (((c0 + 1) ^ (r & 7)) & 7);
        float4 f0 = *(const float4*)&XL[buf][r * 128 + pc0 * 4];
        float4 f1 = *(const float4*)&XL[buf][r * 128 + pc1 * 4];
        intx4 pk;
        pk[0] = (int)__builtin_amdgcn_perm(fbits(f0.y), fbits(f0.x), 0x07060302u);
        pk[1] = (int)__builtin_amdgcn_perm(fbits(f0.w), fbits(f0.z), 0x07060302u);
        pk[2] = (int)__builtin_amdgcn_perm(fbits(f1.y), fbits(f1.x), 0x07060302u);
        pk[3] = (int)__builtin_amdgcn_perm(fbits(f1.w), fbits(f1.z), 0x07060302u);
        a[mt] = __builtin_bit_cast(short8, pk);
      }
#pragma unroll
      for (int mt = 0; mt < 2; ++mt)
#pragma unroll
        for (int nt = 0; nt < 3; ++nt)
          acc[mt][nt] = __builtin_amdgcn_mfma_f32_16x16x32_bf16(a[mt], b[nt], acc[mt][nt], 0, 0, 0);
    }
    __syncthreads();   // prefetch landed + all waves done with buf
  }

  // ---- epilogue: q direct; K,V via LDS into fragment-ready layouts ----
  unsigned short* VTB = (unsigned short*)&XL[0][0];   // [64 h][40] bf16 (V^T)
  unsigned short* KB  = VTB + 5120;                   // [32 t][72] bf16
#pragma unroll
  for (int mt = 0; mt < 2; ++mt)
#pragma unroll
    for (int nt = 0; nt < 3; ++nt) {
      int n = wave * 48 + nt * 16 + lane4;
#pragma unroll
      for (int rr = 0; rr < 4; ++rr) {
        unsigned short val = f2bf(acc[mt][nt][rr]);
        int lrow = mt * 16 + quad * 4 + rr;
        if (n < 64)       qo[(size_t)(m0 + lrow) * H_ + n] = val;
        else if (n < 128) KB[lrow * 72 + (n - 64)] = val;
        else              VTB[(n - 128) * 40 + lrow] = val;
      }
    }
  __syncthreads();
  {
    int bb = m0 >> 11, t0 = m0 & 2047;
    int st = t0 >> 6, off = t0 & 63;
    // K: 256 chunks (ks x ctl x 64 lanes)
    int ks = tid >> 7, ctl = (tid >> 6) & 1, ln = tid & 63;
    int ct = (off >> 4) + ctl;
    int tl = ctl * 16 + (ln & 15);
    int h0 = ks * 32 + (ln >> 4) * 8;
    uint4 kd = *(const uint4*)&KB[tl * 72 + h0];
    *(uint4*)&kf[((size_t)((bb * 32 + st) * 2 + ks) * 4 + ct) * 512 + ln * 8] = kd;
    // V: 256 chunks (nt x 64 lanes), ks fixed = off>>5
    int nt = tid >> 6, l4 = tid & 15, qs = (tid >> 4) & 3;
    int ksv = off >> 5;
    uint4 vd = *(const uint4*)&VTB[(nt * 16 + l4) * 40 + qs * 8];
    *(uint4*)&vf[((size_t)((bb * 32 + st) * 2 + ksv) * 4 + nt) * 512 + (tid & 63) * 8] = vd;
  }
}

// ---------------------------------------------------------------------------
// Kernel 2: causal flash attention, split-4, fixed-max softmax.
// R16 CHANGE: R15's reg-staging spilled (VGPR=68 vs ~100 live -> scratch
// traffic, +30us). Revert to gl_lds DOUBLE-BUFFER staging (R14, no reg
// arrays), and attack the real symptom (Occupancy 13%, all pipes <10% =
// wave starvation + block-refill serialization): QBLK=128, 8 waves, 512
// threads/block. Grid (16,8,4)=512 blocks -> ENTIRE grid resident
// (2 blocks/CU, 16 waves/CU, no refill), K/V staging halves (16 KB feeds
// 128 q-rows), barriers amortized 2x. Diagonal mask on last two tiles
// (st >= 2*qt) with absolute row/col indices. LDS: 2x16KB KV + 18KB PL
// = 50.4 KB. launch_bounds(512,4) caps VGPR at 128 (plenty; no spill).
// ---------------------------------------------------------------------------
__global__ __launch_bounds__(512, 4) void attn(
    const unsigned short* __restrict__ qi, const unsigned short* __restrict__ Kf,
    const unsigned short* __restrict__ Vf, unsigned short* __restrict__ Op,
    float* __restrict__ lsum) {
  __shared__ unsigned short KV[2][8192];   // [buf][ K: 0..4095 | V: 4096..8191 ]
  __shared__ unsigned short PL[8][16][72];

  int tid = threadIdx.x;
  int wave = tid >> 6, lane = tid & 63;
  int lane4 = lane & 15, quad = lane >> 4;
  int qt = 15 - (int)blockIdx.x;   // biggest blocks dispatch first
  int b = blockIdx.y, split = blockIdx.z;
  int qb = qt * 128;
  int base = b * T_;

  int ntile = 2 * qt + 2;
  int sBeg = (split * ntile) >> 2;
  int sEnd = ((split + 1) * ntile) >> 2;

  short8 aq[2];
#pragma unroll
  for (int ks = 0; ks < 2; ++ks)
    aq[ks] = *(const short8*)&qi[(size_t)(base + qb + wave * 16 + lane4) * H_ + ks * 32 + quad * 8];

  float lrow[4];
  floatx4 o[4];
#pragma unroll
  for (int r = 0; r < 4; ++r) lrow[r] = 0.0f;
#pragma unroll
  for (int nt = 0; nt < 4; ++nt) o[nt] = (floatx4)0.0f;

  // stage one 64-row K/V tile (8 KB + 8 KB) into KV[bf]; 2 insts/thread,
  // LDS dest lane-linear (gl_lds constraint).
  auto stage = [&](int st, int bf) {
    size_t tb = (size_t)(b * 32 + st) * 4096;
    gl_lds16(&Kf[tb + (size_t)tid * 8], &KV[bf][tid * 8]);
    gl_lds16(&Vf[tb + (size_t)tid * 8], &KV[bf][4096 + tid * 8]);
  };

  if (sBeg < sEnd) stage(sBeg, 0);
  __syncthreads();   // tile sBeg resident (barrier drains vmcnt)

  for (int st = sBeg; st < sEnd; ++st) {
    int buf = (st - sBeg) & 1;
    if (st + 1 < sEnd) stage(st + 1, buf ^ 1);   // async prefetch into other buf

    floatx4 sacc[4];
#pragma unroll
    for (int ct = 0; ct < 4; ++ct) sacc[ct] = (floatx4)0.0f;
    __builtin_amdgcn_s_setprio(1);
#pragma unroll
    for (int ks = 0; ks < 2; ++ks)
#pragma unroll
      for (int ct = 0; ct < 4; ++ct) {
        short8 bk = *(const short8*)&KV[buf][(ks * 4 + ct) * 512 + lane * 8];
        sacc[ct] = __builtin_amdgcn_mfma_f32_16x16x32_bf16(aq[ks], bk, sacc[ct], 0, 0, 0);
      }
    __builtin_amdgcn_s_setprio(0);

    if (st >= 2 * qt) {   // the two diagonal-crossing tiles: absolute mask
#pragma unroll
      for (int ct = 0; ct < 4; ++ct)
#pragma unroll
        for (int r = 0; r < 4; ++r) {
          int qrow = qb + wave * 16 + quad * 4 + r;
          int scol = st * 64 + ct * 16 + lane4;
          if (scol > qrow) sacc[ct][r] = -3.0e38f;
        }
    }

    // fixed-max softmax: p = exp2(s - 8)
#pragma unroll
    for (int ct = 0; ct < 4; ++ct)
#pragma unroll
      for (int r = 0; r < 4; ++r) {
        float p = exp2f(sacc[ct][r] - 8.0f);
        lrow[r] += p;
        PL[wave][quad * 4 + r][ct * 16 + lane4] = f2bf_t(p);
      }

    // O += P V  (PL write->read same-wave; lgkmcnt orders it)
    __builtin_amdgcn_s_setprio(1);
#pragma unroll
    for (int ks = 0; ks < 2; ++ks) {
      short8 pa = *(const short8*)&PL[wave][lane4][ks * 32 + quad * 8];
#pragma unroll
      for (int nt = 0; nt < 4; ++nt) {
        short8 bv = *(const short8*)&KV[buf][4096 + (ks * 4 + nt) * 512 + lane * 8];
        o[nt] = __builtin_amdgcn_mfma_f32_16x16x32_bf16(pa, bv, o[nt], 0, 0, 0);
      }
    }
    __builtin_amdgcn_s_setprio(0);

    __syncthreads();   // all waves done with buf + prefetch landed
  }

  // epilogue: l-reduce across the 16 lanes of each quad-group
#pragma unroll
  for (int off = 1; off < 16; off <<= 1)
#pragma unroll
    for (int r = 0; r < 4; ++r) lrow[r] += __shfl_xor(lrow[r], off);

  size_t pbase = (((size_t)split * 8 + b) * 16 + qt) * 128;
#pragma unroll
  for (int r = 0; r < 4; ++r) {
    int row = wave * 16 + quad * 4 + r;
#pragma unroll
    for (int nt = 0; nt < 4; ++nt)
      Op[(pbase + row) * 64 + nt * 16 + lane4] = f2bf(o[nt][r]);
    if (lane4 == 0) lsum[pbase + row] = lrow[r];
  }
}

// ---------------------------------------------------------------------------
// Kernel 3: merge the 4 key-range splits: out = sum(O_i) / sum(l_i).
// (index math updated for 128-row q-blocks)
// ---------------------------------------------------------------------------
__global__ __launch_bounds__(256) void merge_splits(
    const unsigned short* __restrict__ Op, const float* __restrict__ lsum,
    float* __restrict__ out) {
  int idx = blockIdx.x * 256 + threadIdx.x;
  int row = idx >> 4;
  int h4 = (idx & 15) * 4;
  int b = row >> 11, t = row & 2047;
  int qt = t >> 7, r = t & 127;
  float O0 = 0.f, O1 = 0.f, O2 = 0.f, O3 = 0.f, l = 0.f;
#pragma unroll
  for (int s = 0; s < 4; ++s) {
    size_t p = (((size_t)s * 8 + b) * 16 + qt) * 128 + r;
    l += lsum[p];
    ushort4 ov = *(const ushort4*)&Op[p * 64 + h4];
    O0 += bf2f(ov.x); O1 += bf2f(ov.y); O2 += bf2f(ov.z); O3 += bf2f(ov.w);
  }
  float inv = 1.0f / l;
  float4 res = make_float4(O0 * inv, O1 * inv, O2 * inv, O3 * inv);
  *(float4*)&out[(size_t)row * H_ + h4] = res;
}

extern "C" void kernel_launch(void* const* d_in, const int* in_sizes, int n_in,
                              void* d_out, int out_size, void* d_ws, size_t ws_size,
                              hipStream_t stream) {
  const float* x  = (const float*)d_in[0];
  const float* wq = (const float*)d_in[1];
  const float* wk = (const float*)d_in[2];
  const float* wv = (const float*)d_in[3];
  float* out = (float*)d_out;

  char* ws = (char*)d_ws;
  unsigned short* wf = (unsigned short*)ws;                    // 393216 B
  unsigned short* qb = (unsigned short*)(ws + 393216);         // 2097152 B
  unsigned short* kf = (unsigned short*)(ws + 2490368);        // 2097152 B (frag-ready)
  unsigned short* vf = (unsigned short*)(ws + 4587520);        // 2097152 B (frag-ready)
  unsigned short* Op = (unsigned short*)(ws + 6684672);        // 8388608 B (4 splits)
  float*          ls = (float*)(ws + 15073280);                // 262144 B (total 15335424)

  conv_w<<<96, 256, 0, stream>>>(wq, wk, wv, wf);
  qkv_proj<<<512, 256, 0, stream>>>(x, wf, qb, kf, vf);
  attn<<<dim3(16, 8, 4), 512, 0, stream>>>(qb, kf, vf, Op, ls);
  merge_splits<<<1024, 256, 0, stream>>>(Op, ls, out);
}

// Round 4
// 125.506 us; speedup vs baseline: 1.2837x; 1.0199x over previous
//
#include <hip/hip_runtime.h>

#define B_ 8
#define T_ 2048
#define C_ 1024
#define H_ 64

typedef __attribute__((ext_vector_type(8))) short short8;
typedef __attribute__((ext_vector_type(4))) float floatx4;
typedef __attribute__((ext_vector_type(4))) int intx4;

static __device__ __forceinline__ unsigned short f2bf(float f) {
  unsigned int u = __builtin_bit_cast(unsigned int, f);
  u += 0x7FFFu + ((u >> 16) & 1u);   // RNE
  return (unsigned short)(u >> 16);
}
static __device__ __forceinline__ float bf2f(unsigned short u) {
  return __builtin_bit_cast(float, ((unsigned int)u) << 16);
}
static __device__ __forceinline__ unsigned int fbits(float f) {
  return __builtin_bit_cast(unsigned int, f);
}

typedef const __attribute__((address_space(1))) unsigned int* gp1_t;
typedef __attribute__((address_space(3))) unsigned int* lp3_t;
static __device__ __forceinline__ void gl_lds16(const void* g, void* l) {
  __builtin_amdgcn_global_load_lds((gp1_t)g, (lp3_t)l, 16, 0, 0);
}

// ---------------------------------------------------------------------------
// Kernel 0: W fp32 -> Wf FRAGMENT-READY bf16 (unchanged).
// ---------------------------------------------------------------------------
__global__ __launch_bounds__(256) void conv_w(const float* __restrict__ wq,
    const float* __restrict__ wk, const float* __restrict__ wv,
    unsigned short* __restrict__ wf) {
  int c = blockIdx.x * 256 + threadIdx.x;   // 24576 chunks
  int lane = c & 63;
  int t = c >> 6;
  int ng = t % 12;
  int kk = t / 12;                           // kt*2+ks, 0..31
  int k0 = kk * 32 + (lane >> 4) * 8;
  int n = ng * 16 + (lane & 15);
  const float* src;
  int col;
  float scale = 1.0f;
  if (n < 64)       { src = wq; col = n;       scale = 0.03125f * 1.44269504088896340736f; }
  else if (n < 128) { src = wk; col = n - 64;  }
  else              { src = wv; col = n - 128; }
  unsigned short o[8];
#pragma unroll
  for (int j = 0; j < 8; ++j) o[j] = f2bf(src[(size_t)(k0 + j) * H_ + col] * scale);
  *(uint4*)&wf[(size_t)c * 8] = *(const uint4*)o;
}

// ---------------------------------------------------------------------------
// Kernel 1: QKV projection. ONLY CHANGE (R17): the V epilogue scatter writes
// Vf with a k-PERMUTED fragment layout -- B-frag slot (quad qb, elem jb) now
// holds t_local = (jb<4 ? 4*qb+jb : 16+4*qb+(jb-4)) within each 32-half --
// matching the natural in-lane order of the swapped-QK^T P fragment in attn.
// (PV is a sum over t; permuting t identically in P and V is exact.)
// ---------------------------------------------------------------------------
__global__ __launch_bounds__(256, 4) void qkv_proj(
    const float* __restrict__ x, const unsigned short* __restrict__ wf,
    unsigned short* __restrict__ qo, unsigned short* __restrict__ kf,
    unsigned short* __restrict__ vf) {
  __shared__ float XL[2][4096];   // 2 x (32 rows x 128 fp32) = 32 KB
  int tid = threadIdx.x;
  int wave = tid >> 6, lane = tid & 63;
  int lane4 = lane & 15, quad = lane >> 4;
  int m0 = blockIdx.x * 32;
  int ph0 = blockIdx.x & 7;       // per-block K-order rotation

  // stage one phase (32 rows x 128 floats = 1024 16B-chunks, 4 insts/thread)
  auto stage_ph = [&](int phr, int buf) {
#pragma unroll
    for (int j = 0; j < 4; ++j) {
      int c = (wave * 4 + j) * 64 + lane;    // chunk id 0..1023
      int r = c >> 5, pc = c & 31;           // 32 chunks per row
      int cl = (pc & ~7) | ((pc ^ (r & 7)) & 7);
      gl_lds16(&x[(size_t)(m0 + r) * C_ + phr * 128 + cl * 4], &XL[buf][c * 4]);
    }
  };

  floatx4 acc[2][3];
#pragma unroll
  for (int mt = 0; mt < 2; ++mt)
#pragma unroll
    for (int nt = 0; nt < 3; ++nt) acc[mt][nt] = (floatx4)0.0f;

  stage_ph(ph0, 0);
  __syncthreads();

  for (int ph = 0; ph < 8; ++ph) {
    int buf = ph & 1;
    if (ph < 7) stage_ph((ph + 1 + ph0) & 7, buf ^ 1);   // async prefetch
    int phr = (ph + ph0) & 7;
#pragma unroll
    for (int sl = 0; sl < 4; ++sl) {
      int s = phr * 4 + sl;            // global ks-step, 0..31
      short8 b[3];
#pragma unroll
      for (int nt = 0; nt < 3; ++nt)
        b[nt] = *(const short8*)&wf[(size_t)(s * 12 + wave * 3 + nt) * 512 + lane * 8];
      short8 a[2];
#pragma unroll
      for (int mt = 0; mt < 2; ++mt) {
        int r = mt * 16 + lane4;
        int c0 = sl * 8 + quad * 2;    // phase-local float4-chunk, 0..31
        int pc0 = (c0 & ~7) | ((c0 ^ (r & 7)) & 7);
        int pc1 = ((c0 + 1) & ~7) | (((c0 + 1) ^ (r & 7)) & 7);
        float4 f0 = *(const float4*)&XL[buf][r * 128 + pc0 * 4];
        float4 f1 = *(const float4*)&XL[buf][r * 128 + pc1 * 4];
        intx4 pk;
        pk[0] = (int)__builtin_amdgcn_perm(fbits(f0.y), fbits(f0.x), 0x07060302u);
        pk[1] = (int)__builtin_amdgcn_perm(fbits(f0.w), fbits(f0.z), 0x07060302u);
        pk[2] = (int)__builtin_amdgcn_perm(fbits(f1.y), fbits(f1.x), 0x07060302u);
        pk[3] = (int)__builtin_amdgcn_perm(fbits(f1.w), fbits(f1.z), 0x07060302u);
        a[mt] = __builtin_bit_cast(short8, pk);
      }
#pragma unroll
      for (int mt = 0; mt < 2; ++mt)
#pragma unroll
        for (int nt = 0; nt < 3; ++nt)
          acc[mt][nt] = __builtin_amdgcn_mfma_f32_16x16x32_bf16(a[mt], b[nt], acc[mt][nt], 0, 0, 0);
    }
    __syncthreads();   // prefetch landed + all waves done with buf
  }

  // ---- epilogue: q direct; K,V via LDS into fragment-ready layouts ----
  unsigned short* VTB = (unsigned short*)&XL[0][0];   // [64 h][40] bf16 (V^T)
  unsigned short* KB  = VTB + 5120;                   // [32 t][72] bf16
#pragma unroll
  for (int mt = 0; mt < 2; ++mt)
#pragma unroll
    for (int nt = 0; nt < 3; ++nt) {
      int n = wave * 48 + nt * 16 + lane4;
#pragma unroll
      for (int rr = 0; rr < 4; ++rr) {
        unsigned short val = f2bf(acc[mt][nt][rr]);
        int lrow = mt * 16 + quad * 4 + rr;
        if (n < 64)       qo[(size_t)(m0 + lrow) * H_ + n] = val;
        else if (n < 128) KB[lrow * 72 + (n - 64)] = val;
        else              VTB[(n - 128) * 40 + lrow] = val;
      }
    }
  __syncthreads();
  {
    int bb = m0 >> 11, t0 = m0 & 2047;
    int st = t0 >> 6, off = t0 & 63;
    // K: 256 chunks (ks x ctl x 64 lanes)
    int ks = tid >> 7, ctl = (tid >> 6) & 1, ln = tid & 63;
    int ct = (off >> 4) + ctl;
    int tl = ctl * 16 + (ln & 15);
    int h0 = ks * 32 + (ln >> 4) * 8;
    uint4 kd = *(const uint4*)&KB[tl * 72 + h0];
    *(uint4*)&kf[((size_t)((bb * 32 + st) * 2 + ks) * 4 + ct) * 512 + ln * 8] = kd;
    // V: 256 chunks (nt x 64 lanes), ks fixed = off>>5; k-permuted frag:
    // slot (qs, j<4) = t 4*qs+j ; slot (qs, j>=4) = t 16+4*qs+(j-4)
    int nt = tid >> 6, l4 = tid & 15, qs = (tid >> 4) & 3;
    int ksv = off >> 5;
    uint2 vlo = *(const uint2*)&VTB[(nt * 16 + l4) * 40 + qs * 4];
    uint2 vhi = *(const uint2*)&VTB[(nt * 16 + l4) * 40 + 16 + qs * 4];
    uint4 vd = make_uint4(vlo.x, vlo.y, vhi.x, vhi.y);
    *(uint4*)&vf[((size_t)((bb * 32 + st) * 2 + ksv) * 4 + nt) * 512 + (tid & 63) * 8] = vd;
  }
}

// ---------------------------------------------------------------------------
// Kernel 2: causal flash attention, split-4, fixed-max softmax.
// R17 CHANGE (in-register softmax, T12-style): compute S^T = mfma(K, Q)
// (operands swapped). Each lane then holds 16 scores of ONE q-row
// (qrow = lane&15; kcol = ct*16 + quad*4 + r). Softmax runs entirely in
// registers; P is packed to bf16 via v_perm (same truncation as the old
// PL path) directly into the PV A-fragment, whose k-order is matched by
// the k-PERMUTED Vf layout written by qkv_proj. The PL LDS round-trip,
// its 16 ds_write_b16 + ds_read + lgkmcnt(0) serialization, and 18 KB of
// LDS are all eliminated. l-reduce: 2 shfl_xor (16, 32). Staging /
// double-buffer / grid / setprio identical to R16.
// ---------------------------------------------------------------------------
__global__ __launch_bounds__(512, 4) void attn(
    const unsigned short* __restrict__ qi, const unsigned short* __restrict__ Kf,
    const unsigned short* __restrict__ Vf, unsigned short* __restrict__ Op,
    float* __restrict__ lsum) {
  __shared__ unsigned short KV[2][8192];   // [buf][ K: 0..4095 | V: 4096..8191 ]

  int tid = threadIdx.x;
  int wave = tid >> 6, lane = tid & 63;
  int lane4 = lane & 15, quad = lane >> 4;
  int qt = 15 - (int)blockIdx.x;   // biggest blocks dispatch first
  int b = blockIdx.y, split = blockIdx.z;
  int qb = qt * 128;
  int base = b * T_;

  int ntile = 2 * qt + 2;
  int sBeg = (split * ntile) >> 2;
  int sEnd = ((split + 1) * ntile) >> 2;

  short8 aq[2];
#pragma unroll
  for (int ks = 0; ks < 2; ++ks)
    aq[ks] = *(const short8*)&qi[(size_t)(base + qb + wave * 16 + lane4) * H_ + ks * 32 + quad * 8];

  float lsumv = 0.0f;
  floatx4 o[4];
#pragma unroll
  for (int nt = 0; nt < 4; ++nt) o[nt] = (floatx4)0.0f;

  // stage one 64-row K/V tile (8 KB + 8 KB) into KV[bf]; 2 insts/thread.
  auto stage = [&](int st, int bf) {
    size_t tb = (size_t)(b * 32 + st) * 4096;
    gl_lds16(&Kf[tb + (size_t)tid * 8], &KV[bf][tid * 8]);
    gl_lds16(&Vf[tb + (size_t)tid * 8], &KV[bf][4096 + tid * 8]);
  };

  if (sBeg < sEnd) stage(sBeg, 0);
  __syncthreads();   // tile sBeg resident (barrier drains vmcnt)

  for (int st = sBeg; st < sEnd; ++st) {
    int buf = (st - sBeg) & 1;
    if (st + 1 < sEnd) stage(st + 1, buf ^ 1);   // async prefetch into other buf

    // S^T = K . Q^T : lane holds S[kcol = ct*16+quad*4+r][qrow = lane4]
    floatx4 sacc[4];
#pragma unroll
    for (int ct = 0; ct < 4; ++ct) sacc[ct] = (floatx4)0.0f;
    __builtin_amdgcn_s_setprio(1);
#pragma unroll
    for (int ks = 0; ks < 2; ++ks)
#pragma unroll
      for (int ct = 0; ct < 4; ++ct) {
        short8 bk = *(const short8*)&KV[buf][(ks * 4 + ct) * 512 + lane * 8];
        sacc[ct] = __builtin_amdgcn_mfma_f32_16x16x32_bf16(bk, aq[ks], sacc[ct], 0, 0, 0);
      }
    __builtin_amdgcn_s_setprio(0);

    if (st >= 2 * qt) {   // the two diagonal-crossing tiles: absolute mask
      int qrow = qb + wave * 16 + lane4;
#pragma unroll
      for (int ct = 0; ct < 4; ++ct)
#pragma unroll
        for (int r = 0; r < 4; ++r) {
          int scol = st * 64 + ct * 16 + quad * 4 + r;
          if (scol > qrow) sacc[ct][r] = -3.0e38f;
        }
    }

    // fixed-max softmax in registers: p = exp2(s - 8); pack bf16 via perm
    unsigned int pk[4][2];
#pragma unroll
    for (int ct = 0; ct < 4; ++ct) {
      float p0 = exp2f(sacc[ct][0] - 8.0f);
      float p1 = exp2f(sacc[ct][1] - 8.0f);
      float p2 = exp2f(sacc[ct][2] - 8.0f);
      float p3 = exp2f(sacc[ct][3] - 8.0f);
      lsumv += (p0 + p1) + (p2 + p3);
      pk[ct][0] = __builtin_amdgcn_perm(fbits(p1), fbits(p0), 0x07060302u);
      pk[ct][1] = __builtin_amdgcn_perm(fbits(p3), fbits(p2), 0x07060302u);
    }

    // O += P V  (pa is register-resident; Vf k-order matches pk layout)
    __builtin_amdgcn_s_setprio(1);
#pragma unroll
    for (int ks = 0; ks < 2; ++ks) {
      intx4 pai;
      pai[0] = (int)pk[2 * ks][0];
      pai[1] = (int)pk[2 * ks][1];
      pai[2] = (int)pk[2 * ks + 1][0];
      pai[3] = (int)pk[2 * ks + 1][1];
      short8 pa = __builtin_bit_cast(short8, pai);
#pragma unroll
      for (int nt = 0; nt < 4; ++nt) {
        short8 bv = *(const short8*)&KV[buf][4096 + (ks * 4 + nt) * 512 + lane * 8];
        o[nt] = __builtin_amdgcn_mfma_f32_16x16x32_bf16(pa, bv, o[nt], 0, 0, 0);
      }
    }
    __builtin_amdgcn_s_setprio(0);

    __syncthreads();   // all waves done with buf + prefetch landed
  }

  // l-reduce: quads {0,1,2,3} of each lane4 hold partials of the same q-row
  lsumv += __shfl_xor(lsumv, 16);
  lsumv += __shfl_xor(lsumv, 32);

  size_t pbase = (((size_t)split * 8 + b) * 16 + qt) * 128;
#pragma unroll
  for (int r = 0; r < 4; ++r) {
    int row = wave * 16 + quad * 4 + r;
#pragma unroll
    for (int nt = 0; nt < 4; ++nt)
      Op[(pbase + row) * 64 + nt * 16 + lane4] = f2bf(o[nt][r]);
  }
  if (quad == 0) lsum[pbase + wave * 16 + lane4] = lsumv;
}

// ---------------------------------------------------------------------------
// Kernel 3: merge the 4 key-range splits: out = sum(O_i) / sum(l_i).
// (unchanged; 128-row q-block indexing)
// ---------------------------------------------------------------------------
__global__ __launch_bounds__(256) void merge_splits(
    const unsigned short* __restrict__ Op, const float* __restrict__ lsum,
    float* __restrict__ out) {
  int idx = blockIdx.x * 256 + threadIdx.x;
  int row = idx >> 4;
  int h4 = (idx & 15) * 4;
  int b = row >> 11, t = row & 2047;
  int qt = t >> 7, r = t & 127;
  float O0 = 0.f, O1 = 0.f, O2 = 0.f, O3 = 0.f, l = 0.f;
#pragma unroll
  for (int s = 0; s < 4; ++s) {
    size_t p = (((size_t)s * 8 + b) * 16 + qt) * 128 + r;
    l += lsum[p];
    ushort4 ov = *(const ushort4*)&Op[p * 64 + h4];
    O0 += bf2f(ov.x); O1 += bf2f(ov.y); O2 += bf2f(ov.z); O3 += bf2f(ov.w);
  }
  float inv = 1.0f / l;
  float4 res = make_float4(O0 * inv, O1 * inv, O2 * inv, O3 * inv);
  *(float4*)&out[(size_t)row * H_ + h4] = res;
}

extern "C" void kernel_launch(void* const* d_in, const int* in_sizes, int n_in,
                              void* d_out, int out_size, void* d_ws, size_t ws_size,
                              hipStream_t stream) {
  const float* x  = (const float*)d_in[0];
  const float* wq = (const float*)d_in[1];
  const float* wk = (const float*)d_in[2];
  const float* wv = (const float*)d_in[3];
  float* out = (float*)d_out;

  char* ws = (char*)d_ws;
  unsigned short* wf = (unsigned short*)ws;                    // 393216 B
  unsigned short* qb = (unsigned short*)(ws + 393216);         // 2097152 B
  unsigned short* kf = (unsigned short*)(ws + 2490368);        // 2097152 B (frag-ready)
  unsigned short* vf = (unsigned short*)(ws + 4587520);        // 2097152 B (frag-ready)
  unsigned short* Op = (unsigned short*)(ws + 6684672);        // 8388608 B (4 splits)
  float*          ls = (float*)(ws + 15073280);                // 262144 B (total 15335424)

  conv_w<<<96, 256, 0, stream>>>(wq, wk, wv, wf);
  qkv_proj<<<512, 256, 0, stream>>>(x, wf, qb, kf, vf);
  attn<<<dim3(16, 8, 4), 512, 0, stream>>>(qb, kf, vf, Op, ls);
  merge_splits<<<1024, 256, 0, stream>>>(Op, ls, out);
}

// Round 5
// 121.870 us; speedup vs baseline: 1.3220x; 1.0298x over previous
//
#include <hip/hip_runtime.h>

#define B_ 8
#define T_ 2048
#define C_ 1024
#define H_ 64

typedef __attribute__((ext_vector_type(8))) short short8;
typedef __attribute__((ext_vector_type(4))) float floatx4;
typedef __attribute__((ext_vector_type(4))) int intx4;

static __device__ __forceinline__ unsigned short f2bf(float f) {
  unsigned int u = __builtin_bit_cast(unsigned int, f);
  u += 0x7FFFu + ((u >> 16) & 1u);   // RNE
  return (unsigned short)(u >> 16);
}
static __device__ __forceinline__ float bf2f(unsigned short u) {
  return __builtin_bit_cast(float, ((unsigned int)u) << 16);
}
static __device__ __forceinline__ unsigned int fbits(float f) {
  return __builtin_bit_cast(unsigned int, f);
}

typedef const __attribute__((address_space(1))) unsigned int* gp1_t;
typedef __attribute__((address_space(3))) unsigned int* lp3_t;
static __device__ __forceinline__ void gl_lds16(const void* g, void* l) {
  __builtin_amdgcn_global_load_lds((gp1_t)g, (lp3_t)l, 16, 0, 0);
}

// ---------------------------------------------------------------------------
// Kernel 0: W fp32 -> Wf FRAGMENT-READY bf16 (unchanged).
// ---------------------------------------------------------------------------
__global__ __launch_bounds__(256) void conv_w(const float* __restrict__ wq,
    const float* __restrict__ wk, const float* __restrict__ wv,
    unsigned short* __restrict__ wf) {
  int c = blockIdx.x * 256 + threadIdx.x;   // 24576 chunks
  int lane = c & 63;
  int t = c >> 6;
  int ng = t % 12;
  int kk = t / 12;                           // kt*2+ks, 0..31
  int k0 = kk * 32 + (lane >> 4) * 8;
  int n = ng * 16 + (lane & 15);
  const float* src;
  int col;
  float scale = 1.0f;
  if (n < 64)       { src = wq; col = n;       scale = 0.03125f * 1.44269504088896340736f; }
  else if (n < 128) { src = wk; col = n - 64;  }
  else              { src = wv; col = n - 128; }
  unsigned short o[8];
#pragma unroll
  for (int j = 0; j < 8; ++j) o[j] = f2bf(src[(size_t)(k0 + j) * H_ + col] * scale);
  *(uint4*)&wf[(size_t)c * 8] = *(const uint4*)o;
}

// ---------------------------------------------------------------------------
// Kernel 1: QKV projection (unchanged this round; isolating the attn change).
// V epilogue writes Vf k-PERMUTED to match the swapped-QK^T P fragment.
// ---------------------------------------------------------------------------
__global__ __launch_bounds__(256, 4) void qkv_proj(
    const float* __restrict__ x, const unsigned short* __restrict__ wf,
    unsigned short* __restrict__ qo, unsigned short* __restrict__ kf,
    unsigned short* __restrict__ vf) {
  __shared__ float XL[2][4096];   // 2 x (32 rows x 128 fp32) = 32 KB
  int tid = threadIdx.x;
  int wave = tid >> 6, lane = tid & 63;
  int lane4 = lane & 15, quad = lane >> 4;
  int m0 = blockIdx.x * 32;
  int ph0 = blockIdx.x & 7;       // per-block K-order rotation

  // stage one phase (32 rows x 128 floats = 1024 16B-chunks, 4 insts/thread)
  auto stage_ph = [&](int phr, int buf) {
#pragma unroll
    for (int j = 0; j < 4; ++j) {
      int c = (wave * 4 + j) * 64 + lane;    // chunk id 0..1023
      int r = c >> 5, pc = c & 31;           // 32 chunks per row
      int cl = (pc & ~7) | ((pc ^ (r & 7)) & 7);
      gl_lds16(&x[(size_t)(m0 + r) * C_ + phr * 128 + cl * 4], &XL[buf][c * 4]);
    }
  };

  floatx4 acc[2][3];
#pragma unroll
  for (int mt = 0; mt < 2; ++mt)
#pragma unroll
    for (int nt = 0; nt < 3; ++nt) acc[mt][nt] = (floatx4)0.0f;

  stage_ph(ph0, 0);
  __syncthreads();

  for (int ph = 0; ph < 8; ++ph) {
    int buf = ph & 1;
    if (ph < 7) stage_ph((ph + 1 + ph0) & 7, buf ^ 1);   // async prefetch
    int phr = (ph + ph0) & 7;
#pragma unroll
    for (int sl = 0; sl < 4; ++sl) {
      int s = phr * 4 + sl;            // global ks-step, 0..31
      short8 b[3];
#pragma unroll
      for (int nt = 0; nt < 3; ++nt)
        b[nt] = *(const short8*)&wf[(size_t)(s * 12 + wave * 3 + nt) * 512 + lane * 8];
      short8 a[2];
#pragma unroll
      for (int mt = 0; mt < 2; ++mt) {
        int r = mt * 16 + lane4;
        int c0 = sl * 8 + quad * 2;    // phase-local float4-chunk, 0..31
        int pc0 = (c0 & ~7) | ((c0 ^ (r & 7)) & 7);
        int pc1 = ((c0 + 1) & ~7) | (((c0 + 1) ^ (r & 7)) & 7);
        float4 f0 = *(const float4*)&XL[buf][r * 128 + pc0 * 4];
        float4 f1 = *(const float4*)&XL[buf][r * 128 + pc1 * 4];
        intx4 pk;
        pk[0] = (int)__builtin_amdgcn_perm(fbits(f0.y), fbits(f0.x), 0x07060302u);
        pk[1] = (int)__builtin_amdgcn_perm(fbits(f0.w), fbits(f0.z), 0x07060302u);
        pk[2] = (int)__builtin_amdgcn_perm(fbits(f1.y), fbits(f1.x), 0x07060302u);
        pk[3] = (int)__builtin_amdgcn_perm(fbits(f1.w), fbits(f1.z), 0x07060302u);
        a[mt] = __builtin_bit_cast(short8, pk);
      }
#pragma unroll
      for (int mt = 0; mt < 2; ++mt)
#pragma unroll
        for (int nt = 0; nt < 3; ++nt)
          acc[mt][nt] = __builtin_amdgcn_mfma_f32_16x16x32_bf16(a[mt], b[nt], acc[mt][nt], 0, 0, 0);
    }
    __syncthreads();   // prefetch landed + all waves done with buf
  }

  // ---- epilogue: q direct; K,V via LDS into fragment-ready layouts ----
  unsigned short* VTB = (unsigned short*)&XL[0][0];   // [64 h][40] bf16 (V^T)
  unsigned short* KB  = VTB + 5120;                   // [32 t][72] bf16
#pragma unroll
  for (int mt = 0; mt < 2; ++mt)
#pragma unroll
    for (int nt = 0; nt < 3; ++nt) {
      int n = wave * 48 + nt * 16 + lane4;
#pragma unroll
      for (int rr = 0; rr < 4; ++rr) {
        unsigned short val = f2bf(acc[mt][nt][rr]);
        int lrow = mt * 16 + quad * 4 + rr;
        if (n < 64)       qo[(size_t)(m0 + lrow) * H_ + n] = val;
        else if (n < 128) KB[lrow * 72 + (n - 64)] = val;
        else              VTB[(n - 128) * 40 + lrow] = val;
      }
    }
  __syncthreads();
  {
    int bb = m0 >> 11, t0 = m0 & 2047;
    int st = t0 >> 6, off = t0 & 63;
    // K: 256 chunks (ks x ctl x 64 lanes)
    int ks = tid >> 7, ctl = (tid >> 6) & 1, ln = tid & 63;
    int ct = (off >> 4) + ctl;
    int tl = ctl * 16 + (ln & 15);
    int h0 = ks * 32 + (ln >> 4) * 8;
    uint4 kd = *(const uint4*)&KB[tl * 72 + h0];
    *(uint4*)&kf[((size_t)((bb * 32 + st) * 2 + ks) * 4 + ct) * 512 + ln * 8] = kd;
    // V: 256 chunks (nt x 64 lanes), ks fixed = off>>5; k-permuted frag:
    // slot (qs, j<4) = t 4*qs+j ; slot (qs, j>=4) = t 16+4*qs+(j-4)
    int nt = tid >> 6, l4 = tid & 15, qs = (tid >> 4) & 3;
    int ksv = off >> 5;
    uint2 vlo = *(const uint2*)&VTB[(nt * 16 + l4) * 40 + qs * 4];
    uint2 vhi = *(const uint2*)&VTB[(nt * 16 + l4) * 40 + 16 + qs * 4];
    uint4 vd = make_uint4(vlo.x, vlo.y, vhi.x, vhi.y);
    *(uint4*)&vf[((size_t)((bb * 32 + st) * 2 + ksv) * 4 + nt) * 512 + (tid & 63) * 8] = vd;
  }
}

// ---------------------------------------------------------------------------
// Kernel 2: causal flash attention, split-4, in-register fixed-max softmax.
// R18 CHANGE (load balance via dispatch-pairing): with 512 blocks at
// 2 blocks/CU, breadth-first dispatch gives CU c blocks {c, c+256} --
// which share blockIdx.x (ids differ by 128*2 in z), i.e. the SAME qt.
// A qt=15 CU did 2x8=16 tiles while a qt=0 CU did ~1 -> ~1.9x tail.
// Remap: qt = (z<2) ? 15-x : x, split = z. Coverage is bijective (qt=q:
// splits {0,1} from x=15-q, splits {2,3} from x=q), and each CU's pair
// now carries qt and 15-qt -> ~9 tiles/CU CONSTANT. If dispatch order
// differs, distribution is no worse than before. Everything else
// (staging, swapped-QK^T in-register softmax, setprio, epilogue)
// unchanged from R17.
// ---------------------------------------------------------------------------
__global__ __launch_bounds__(512, 4) void attn(
    const unsigned short* __restrict__ qi, const unsigned short* __restrict__ Kf,
    const unsigned short* __restrict__ Vf, unsigned short* __restrict__ Op,
    float* __restrict__ lsum) {
  __shared__ unsigned short KV[2][8192];   // [buf][ K: 0..4095 | V: 4096..8191 ]

  int tid = threadIdx.x;
  int wave = tid >> 6, lane = tid & 63;
  int lane4 = lane & 15, quad = lane >> 4;
  int split = blockIdx.z;
  int qt = (split < 2) ? (15 - (int)blockIdx.x) : (int)blockIdx.x;
  int b = blockIdx.y;
  int qb = qt * 128;
  int base = b * T_;

  int ntile = 2 * qt + 2;
  int sBeg = (split * ntile) >> 2;
  int sEnd = ((split + 1) * ntile) >> 2;

  short8 aq[2];
#pragma unroll
  for (int ks = 0; ks < 2; ++ks)
    aq[ks] = *(const short8*)&qi[(size_t)(base + qb + wave * 16 + lane4) * H_ + ks * 32 + quad * 8];

  float lsumv = 0.0f;
  floatx4 o[4];
#pragma unroll
  for (int nt = 0; nt < 4; ++nt) o[nt] = (floatx4)0.0f;

  // stage one 64-row K/V tile (8 KB + 8 KB) into KV[bf]; 2 insts/thread.
  auto stage = [&](int st, int bf) {
    size_t tb = (size_t)(b * 32 + st) * 4096;
    gl_lds16(&Kf[tb + (size_t)tid * 8], &KV[bf][tid * 8]);
    gl_lds16(&Vf[tb + (size_t)tid * 8], &KV[bf][4096 + tid * 8]);
  };

  if (sBeg < sEnd) stage(sBeg, 0);
  __syncthreads();   // tile sBeg resident (barrier drains vmcnt)

  for (int st = sBeg; st < sEnd; ++st) {
    int buf = (st - sBeg) & 1;
    if (st + 1 < sEnd) stage(st + 1, buf ^ 1);   // async prefetch into other buf

    // S^T = K . Q^T : lane holds S[kcol = ct*16+quad*4+r][qrow = lane4]
    floatx4 sacc[4];
#pragma unroll
    for (int ct = 0; ct < 4; ++ct) sacc[ct] = (floatx4)0.0f;
    __builtin_amdgcn_s_setprio(1);
#pragma unroll
    for (int ks = 0; ks < 2; ++ks)
#pragma unroll
      for (int ct = 0; ct < 4; ++ct) {
        short8 bk = *(const short8*)&KV[buf][(ks * 4 + ct) * 512 + lane * 8];
        sacc[ct] = __builtin_amdgcn_mfma_f32_16x16x32_bf16(bk, aq[ks], sacc[ct], 0, 0, 0);
      }
    __builtin_amdgcn_s_setprio(0);

    if (st >= 2 * qt) {   // the two diagonal-crossing tiles: absolute mask
      int qrow = qb + wave * 16 + lane4;
#pragma unroll
      for (int ct = 0; ct < 4; ++ct)
#pragma unroll
        for (int r = 0; r < 4; ++r) {
          int scol = st * 64 + ct * 16 + quad * 4 + r;
          if (scol > qrow) sacc[ct][r] = -3.0e38f;
        }
    }

    // fixed-max softmax in registers: p = exp2(s - 8); pack bf16 via perm
    unsigned int pk[4][2];
#pragma unroll
    for (int ct = 0; ct < 4; ++ct) {
      float p0 = exp2f(sacc[ct][0] - 8.0f);
      float p1 = exp2f(sacc[ct][1] - 8.0f);
      float p2 = exp2f(sacc[ct][2] - 8.0f);
      float p3 = exp2f(sacc[ct][3] - 8.0f);
      lsumv += (p0 + p1) + (p2 + p3);
      pk[ct][0] = __builtin_amdgcn_perm(fbits(p1), fbits(p0), 0x07060302u);
      pk[ct][1] = __builtin_amdgcn_perm(fbits(p3), fbits(p2), 0x07060302u);
    }

    // O += P V  (pa is register-resident; Vf k-order matches pk layout)
    __builtin_amdgcn_s_setprio(1);
#pragma unroll
    for (int ks = 0; ks < 2; ++ks) {
      intx4 pai;
      pai[0] = (int)pk[2 * ks][0];
      pai[1] = (int)pk[2 * ks][1];
      pai[2] = (int)pk[2 * ks + 1][0];
      pai[3] = (int)pk[2 * ks + 1][1];
      short8 pa = __builtin_bit_cast(short8, pai);
#pragma unroll
      for (int nt = 0; nt < 4; ++nt) {
        short8 bv = *(const short8*)&KV[buf][4096 + (ks * 4 + nt) * 512 + lane * 8];
        o[nt] = __builtin_amdgcn_mfma_f32_16x16x32_bf16(pa, bv, o[nt], 0, 0, 0);
      }
    }
    __builtin_amdgcn_s_setprio(0);

    __syncthreads();   // all waves done with buf + prefetch landed
  }

  // l-reduce: quads {0,1,2,3} of each lane4 hold partials of the same q-row
  lsumv += __shfl_xor(lsumv, 16);
  lsumv += __shfl_xor(lsumv, 32);

  size_t pbase = (((size_t)split * 8 + b) * 16 + qt) * 128;
#pragma unroll
  for (int r = 0; r < 4; ++r) {
    int row = wave * 16 + quad * 4 + r;
#pragma unroll
    for (int nt = 0; nt < 4; ++nt)
      Op[(pbase + row) * 64 + nt * 16 + lane4] = f2bf(o[nt][r]);
  }
  if (quad == 0) lsum[pbase + wave * 16 + lane4] = lsumv;
}

// ---------------------------------------------------------------------------
// Kernel 3: merge the 4 key-range splits: out = sum(O_i) / sum(l_i).
// (unchanged; 128-row q-block indexing)
// ---------------------------------------------------------------------------
__global__ __launch_bounds__(256) void merge_splits(
    const unsigned short* __restrict__ Op, const float* __restrict__ lsum,
    float* __restrict__ out) {
  int idx = blockIdx.x * 256 + threadIdx.x;
  int row = idx >> 4;
  int h4 = (idx & 15) * 4;
  int b = row >> 11, t = row & 2047;
  int qt = t >> 7, r = t & 127;
  float O0 = 0.f, O1 = 0.f, O2 = 0.f, O3 = 0.f, l = 0.f;
#pragma unroll
  for (int s = 0; s < 4; ++s) {
    size_t p = (((size_t)s * 8 + b) * 16 + qt) * 128 + r;
    l += lsum[p];
    ushort4 ov = *(const ushort4*)&Op[p * 64 + h4];
    O0 += bf2f(ov.x); O1 += bf2f(ov.y); O2 += bf2f(ov.z); O3 += bf2f(ov.w);
  }
  float inv = 1.0f / l;
  float4 res = make_float4(O0 * inv, O1 * inv, O2 * inv, O3 * inv);
  *(float4*)&out[(size_t)row * H_ + h4] = res;
}

extern "C" void kernel_launch(void* const* d_in, const int* in_sizes, int n_in,
                              void* d_out, int out_size, void* d_ws, size_t ws_size,
                              hipStream_t stream) {
  const float* x  = (const float*)d_in[0];
  const float* wq = (const float*)d_in[1];
  const float* wk = (const float*)d_in[2];
  const float* wv = (const float*)d_in[3];
  float* out = (float*)d_out;

  char* ws = (char*)d_ws;
  unsigned short* wf = (unsigned short*)ws;                    // 393216 B
  unsigned short* qb = (unsigned short*)(ws + 393216);         // 2097152 B
  unsigned short* kf = (unsigned short*)(ws + 2490368);        // 2097152 B (frag-ready)
  unsigned short* vf = (unsigned short*)(ws + 4587520);        // 2097152 B (frag-ready)
  unsigned short* Op = (unsigned short*)(ws + 6684672);        // 8388608 B (4 splits)
  float*          ls = (float*)(ws + 15073280);                // 262144 B (total 15335424)

  conv_w<<<96, 256, 0, stream>>>(wq, wk, wv, wf);
  qkv_proj<<<512, 256, 0, stream>>>(x, wf, qb, kf, vf);
  attn<<<dim3(16, 8, 4), 512, 0, stream>>>(qb, kf, vf, Op, ls);
  merge_splits<<<1024, 256, 0, stream>>>(Op, ls, out);
}

// Round 6
// 121.619 us; speedup vs baseline: 1.3247x; 1.0021x over previous
//
#include <hip/hip_runtime.h>

#define B_ 8
#define T_ 2048
#define C_ 1024
#define H_ 64

typedef __attribute__((ext_vector_type(8))) short short8;
typedef __attribute__((ext_vector_type(4))) float floatx4;
typedef __attribute__((ext_vector_type(4))) int intx4;

static __device__ __forceinline__ unsigned short f2bf(float f) {
  unsigned int u = __builtin_bit_cast(unsigned int, f);
  u += 0x7FFFu + ((u >> 16) & 1u);   // RNE
  return (unsigned short)(u >> 16);
}
static __device__ __forceinline__ float bf2f(unsigned short u) {
  return __builtin_bit_cast(float, ((unsigned int)u) << 16);
}
static __device__ __forceinline__ unsigned int fbits(float f) {
  return __builtin_bit_cast(unsigned int, f);
}

typedef const __attribute__((address_space(1))) unsigned int* gp1_t;
typedef __attribute__((address_space(3))) unsigned int* lp3_t;
static __device__ __forceinline__ void gl_lds16(const void* g, void* l) {
  __builtin_amdgcn_global_load_lds((gp1_t)g, (lp3_t)l, 16, 0, 0);
}

// ---------------------------------------------------------------------------
// Kernel 0: W fp32 -> Wf FRAGMENT-READY bf16 (unchanged).
// ---------------------------------------------------------------------------
__global__ __launch_bounds__(256) void conv_w(const float* __restrict__ wq,
    const float* __restrict__ wk, const float* __restrict__ wv,
    unsigned short* __restrict__ wf) {
  int c = blockIdx.x * 256 + threadIdx.x;   // 24576 chunks
  int lane = c & 63;
  int t = c >> 6;
  int ng = t % 12;
  int kk = t / 12;                           // kt*2+ks, 0..31
  int k0 = kk * 32 + (lane >> 4) * 8;
  int n = ng * 16 + (lane & 15);
  const float* src;
  int col;
  float scale = 1.0f;
  if (n < 64)       { src = wq; col = n;       scale = 0.03125f * 1.44269504088896340736f; }
  else if (n < 128) { src = wk; col = n - 64;  }
  else              { src = wv; col = n - 128; }
  unsigned short o[8];
#pragma unroll
  for (int j = 0; j < 8; ++j) o[j] = f2bf(src[(size_t)(k0 + j) * H_ + col] * scale);
  *(uint4*)&wf[(size_t)c * 8] = *(const uint4*)o;
}

// ---------------------------------------------------------------------------
// Kernel 1: QKV projection (unchanged this round; isolating the attn change).
// V epilogue writes Vf k-PERMUTED to match the swapped-QK^T P fragment.
// ---------------------------------------------------------------------------
__global__ __launch_bounds__(256, 4) void qkv_proj(
    const float* __restrict__ x, const unsigned short* __restrict__ wf,
    unsigned short* __restrict__ qo, unsigned short* __restrict__ kf,
    unsigned short* __restrict__ vf) {
  __shared__ float XL[2][4096];   // 2 x (32 rows x 128 fp32) = 32 KB
  int tid = threadIdx.x;
  int wave = tid >> 6, lane = tid & 63;
  int lane4 = lane & 15, quad = lane >> 4;
  int m0 = blockIdx.x * 32;
  int ph0 = blockIdx.x & 7;       // per-block K-order rotation

  // stage one phase (32 rows x 128 floats = 1024 16B-chunks, 4 insts/thread)
  auto stage_ph = [&](int phr, int buf) {
#pragma unroll
    for (int j = 0; j < 4; ++j) {
      int c = (wave * 4 + j) * 64 + lane;    // chunk id 0..1023
      int r = c >> 5, pc = c & 31;           // 32 chunks per row
      int cl = (pc & ~7) | ((pc ^ (r & 7)) & 7);
      gl_lds16(&x[(size_t)(m0 + r) * C_ + phr * 128 + cl * 4], &XL[buf][c * 4]);
    }
  };

  floatx4 acc[2][3];
#pragma unroll
  for (int mt = 0; mt < 2; ++mt)
#pragma unroll
    for (int nt = 0; nt < 3; ++nt) acc[mt][nt] = (floatx4)0.0f;

  stage_ph(ph0, 0);
  __syncthreads();

  for (int ph = 0; ph < 8; ++ph) {
    int buf = ph & 1;
    if (ph < 7) stage_ph((ph + 1 + ph0) & 7, buf ^ 1);   // async prefetch
    int phr = (ph + ph0) & 7;
#pragma unroll
    for (int sl = 0; sl < 4; ++sl) {
      int s = phr * 4 + sl;            // global ks-step, 0..31
      short8 b[3];
#pragma unroll
      for (int nt = 0; nt < 3; ++nt)
        b[nt] = *(const short8*)&wf[(size_t)(s * 12 + wave * 3 + nt) * 512 + lane * 8];
      short8 a[2];
#pragma unroll
      for (int mt = 0; mt < 2; ++mt) {
        int r = mt * 16 + lane4;
        int c0 = sl * 8 + quad * 2;    // phase-local float4-chunk, 0..31
        int pc0 = (c0 & ~7) | ((c0 ^ (r & 7)) & 7);
        int pc1 = ((c0 + 1) & ~7) | (((c0 + 1) ^ (r & 7)) & 7);
        float4 f0 = *(const float4*)&XL[buf][r * 128 + pc0 * 4];
        float4 f1 = *(const float4*)&XL[buf][r * 128 + pc1 * 4];
        intx4 pk;
        pk[0] = (int)__builtin_amdgcn_perm(fbits(f0.y), fbits(f0.x), 0x07060302u);
        pk[1] = (int)__builtin_amdgcn_perm(fbits(f0.w), fbits(f0.z), 0x07060302u);
        pk[2] = (int)__builtin_amdgcn_perm(fbits(f1.y), fbits(f1.x), 0x07060302u);
        pk[3] = (int)__builtin_amdgcn_perm(fbits(f1.w), fbits(f1.z), 0x07060302u);
        a[mt] = __builtin_bit_cast(short8, pk);
      }
#pragma unroll
      for (int mt = 0; mt < 2; ++mt)
#pragma unroll
        for (int nt = 0; nt < 3; ++nt)
          acc[mt][nt] = __builtin_amdgcn_mfma_f32_16x16x32_bf16(a[mt], b[nt], acc[mt][nt], 0, 0, 0);
    }
    __syncthreads();   // prefetch landed + all waves done with buf
  }

  // ---- epilogue: q direct; K,V via LDS into fragment-ready layouts ----
  unsigned short* VTB = (unsigned short*)&XL[0][0];   // [64 h][40] bf16 (V^T)
  unsigned short* KB  = VTB + 5120;                   // [32 t][72] bf16
#pragma unroll
  for (int mt = 0; mt < 2; ++mt)
#pragma unroll
    for (int nt = 0; nt < 3; ++nt) {
      int n = wave * 48 + nt * 16 + lane4;
#pragma unroll
      for (int rr = 0; rr < 4; ++rr) {
        unsigned short val = f2bf(acc[mt][nt][rr]);
        int lrow = mt * 16 + quad * 4 + rr;
        if (n < 64)       qo[(size_t)(m0 + lrow) * H_ + n] = val;
        else if (n < 128) KB[lrow * 72 + (n - 64)] = val;
        else              VTB[(n - 128) * 40 + lrow] = val;
      }
    }
  __syncthreads();
  {
    int bb = m0 >> 11, t0 = m0 & 2047;
    int st = t0 >> 6, off = t0 & 63;
    // K: 256 chunks (ks x ctl x 64 lanes)
    int ks = tid >> 7, ctl = (tid >> 6) & 1, ln = tid & 63;
    int ct = (off >> 4) + ctl;
    int tl = ctl * 16 + (ln & 15);
    int h0 = ks * 32 + (ln >> 4) * 8;
    uint4 kd = *(const uint4*)&KB[tl * 72 + h0];
    *(uint4*)&kf[((size_t)((bb * 32 + st) * 2 + ks) * 4 + ct) * 512 + ln * 8] = kd;
    // V: 256 chunks (nt x 64 lanes), ks fixed = off>>5; k-permuted frag:
    // slot (qs, j<4) = t 4*qs+j ; slot (qs, j>=4) = t 16+4*qs+(j-4)
    int nt = tid >> 6, l4 = tid & 15, qs = (tid >> 4) & 3;
    int ksv = off >> 5;
    uint2 vlo = *(const uint2*)&VTB[(nt * 16 + l4) * 40 + qs * 4];
    uint2 vhi = *(const uint2*)&VTB[(nt * 16 + l4) * 40 + 16 + qs * 4];
    uint4 vd = make_uint4(vlo.x, vlo.y, vhi.x, vhi.y);
    *(uint4*)&vf[((size_t)((bb * 32 + st) * 2 + ksv) * 4 + nt) * 512 + (tid & 63) * 8] = vd;
  }
}

// ---------------------------------------------------------------------------
// Kernel 2: causal flash attention, split-4, in-register fixed-max softmax,
// qt<->15-qt dispatch pairing (R18).
// R19 CHANGE (T3/T4 counted-vmcnt pipeline): __syncthreads per tile emitted
// `s_waitcnt vmcnt(0) lgkmcnt(0)` -- every tile drained the JUST-ISSUED
// prefetch (L2/HBM latency 300-900cy > the ~500cy compute phase), exposing
// hundreds of cycles/tile. Now: 3 LDS buffers (48 KB), depth-2 prefetch,
// ONE raw barrier per tile:
//   s_waitcnt vmcnt(2) ; s_barrier ; issue stage(t+2) ; compute(buf t)
// stage(t) has >=2 strictly-newer gl_lds (stage(t+1)) -> vmcnt(2) + in-order
// retirement guarantees it landed for this wave; the barrier extends that to
// all waves. stage(t+2) overwrites the buffer last read in iter t-1, which
// all waves finished before this barrier. Tail: clamped redundant re-stage
// keeps per-wave vmcnt counts uniform. sched_barrier(0) after the asm
// waitcnt (rule #18). Prefetch now has a full iteration+ to land.
// ---------------------------------------------------------------------------
__global__ __launch_bounds__(512, 4) void attn(
    const unsigned short* __restrict__ qi, const unsigned short* __restrict__ Kf,
    const unsigned short* __restrict__ Vf, unsigned short* __restrict__ Op,
    float* __restrict__ lsum) {
  __shared__ unsigned short KV[3][8192];   // [buf][ K: 0..4095 | V: 4096..8191 ]

  int tid = threadIdx.x;
  int wave = tid >> 6, lane = tid & 63;
  int lane4 = lane & 15, quad = lane >> 4;
  int split = blockIdx.z;
  int qt = (split < 2) ? (15 - (int)blockIdx.x) : (int)blockIdx.x;
  int b = blockIdx.y;
  int qb = qt * 128;
  int base = b * T_;

  int ntile = 2 * qt + 2;
  int sBeg = (split * ntile) >> 2;
  int sEnd = ((split + 1) * ntile) >> 2;
  int last = sEnd - 1;

  short8 aq[2];
#pragma unroll
  for (int ks = 0; ks < 2; ++ks)
    aq[ks] = *(const short8*)&qi[(size_t)(base + qb + wave * 16 + lane4) * H_ + ks * 32 + quad * 8];

  float lsumv = 0.0f;
  floatx4 o[4];
#pragma unroll
  for (int nt = 0; nt < 4; ++nt) o[nt] = (floatx4)0.0f;

  // stage one 64-row K/V tile (8 KB + 8 KB) into KV[bf]; 2 insts/thread.
  auto stage = [&](int st, int bf) {
    size_t tb = (size_t)(b * 32 + st) * 4096;
    gl_lds16(&Kf[tb + (size_t)tid * 8], &KV[bf][tid * 8]);
    gl_lds16(&Vf[tb + (size_t)tid * 8], &KV[bf][4096 + tid * 8]);
  };

  if (sBeg < sEnd) {
    // depth-2 prologue (clamped: redundant re-stage keeps counts uniform)
    stage(sBeg, 0);
    {
      int s1 = sBeg + 1 <= last ? sBeg + 1 : last;
      stage(s1, 1);
    }

    for (int it = 0; it < sEnd - sBeg; ++it) {
      int st = sBeg + it;
      int buf = it % 3;

      // stage(st) landed (>=2 newer gl_lds exist); align all waves.
      asm volatile("s_waitcnt vmcnt(2)" ::: "memory");
      __builtin_amdgcn_sched_barrier(0);
      __builtin_amdgcn_s_barrier();

      // issue stage(st+2): overwrites the buffer last read in iter it-1,
      // which every wave finished before the barrier above.
      {
        int s2 = st + 2 <= last ? st + 2 : last;
        stage(s2, (it + 2) % 3);
      }

      // S^T = K . Q^T : lane holds S[kcol = ct*16+quad*4+r][qrow = lane4]
      floatx4 sacc[4];
#pragma unroll
      for (int ct = 0; ct < 4; ++ct) sacc[ct] = (floatx4)0.0f;
      __builtin_amdgcn_s_setprio(1);
#pragma unroll
      for (int ks = 0; ks < 2; ++ks)
#pragma unroll
        for (int ct = 0; ct < 4; ++ct) {
          short8 bk = *(const short8*)&KV[buf][(ks * 4 + ct) * 512 + lane * 8];
          sacc[ct] = __builtin_amdgcn_mfma_f32_16x16x32_bf16(bk, aq[ks], sacc[ct], 0, 0, 0);
        }
      __builtin_amdgcn_s_setprio(0);

      if (st >= 2 * qt) {   // the two diagonal-crossing tiles: absolute mask
        int qrow = qb + wave * 16 + lane4;
#pragma unroll
        for (int ct = 0; ct < 4; ++ct)
#pragma unroll
          for (int r = 0; r < 4; ++r) {
            int scol = st * 64 + ct * 16 + quad * 4 + r;
            if (scol > qrow) sacc[ct][r] = -3.0e38f;
          }
      }

      // fixed-max softmax in registers: p = exp2(s - 8); pack bf16 via perm
      unsigned int pk[4][2];
#pragma unroll
      for (int ct = 0; ct < 4; ++ct) {
        float p0 = exp2f(sacc[ct][0] - 8.0f);
        float p1 = exp2f(sacc[ct][1] - 8.0f);
        float p2 = exp2f(sacc[ct][2] - 8.0f);
        float p3 = exp2f(sacc[ct][3] - 8.0f);
        lsumv += (p0 + p1) + (p2 + p3);
        pk[ct][0] = __builtin_amdgcn_perm(fbits(p1), fbits(p0), 0x07060302u);
        pk[ct][1] = __builtin_amdgcn_perm(fbits(p3), fbits(p2), 0x07060302u);
      }

      // O += P V  (pa register-resident; Vf k-order matches pk layout)
      __builtin_amdgcn_s_setprio(1);
#pragma unroll
      for (int ks = 0; ks < 2; ++ks) {
        intx4 pai;
        pai[0] = (int)pk[2 * ks][0];
        pai[1] = (int)pk[2 * ks][1];
        pai[2] = (int)pk[2 * ks + 1][0];
        pai[3] = (int)pk[2 * ks + 1][1];
        short8 pa = __builtin_bit_cast(short8, pai);
#pragma unroll
        for (int nt = 0; nt < 4; ++nt) {
          short8 bv = *(const short8*)&KV[buf][4096 + (ks * 4 + nt) * 512 + lane * 8];
          o[nt] = __builtin_amdgcn_mfma_f32_16x16x32_bf16(pa, bv, o[nt], 0, 0, 0);
        }
      }
      __builtin_amdgcn_s_setprio(0);
    }
  }

  // l-reduce: quads {0,1,2,3} of each lane4 hold partials of the same q-row
  lsumv += __shfl_xor(lsumv, 16);
  lsumv += __shfl_xor(lsumv, 32);

  size_t pbase = (((size_t)split * 8 + b) * 16 + qt) * 128;
#pragma unroll
  for (int r = 0; r < 4; ++r) {
    int row = wave * 16 + quad * 4 + r;
#pragma unroll
    for (int nt = 0; nt < 4; ++nt)
      Op[(pbase + row) * 64 + nt * 16 + lane4] = f2bf(o[nt][r]);
  }
  if (quad == 0) lsum[pbase + wave * 16 + lane4] = lsumv;
}

// ---------------------------------------------------------------------------
// Kernel 3: merge the 4 key-range splits: out = sum(O_i) / sum(l_i).
// (unchanged; 128-row q-block indexing)
// ---------------------------------------------------------------------------
__global__ __launch_bounds__(256) void merge_splits(
    const unsigned short* __restrict__ Op, const float* __restrict__ lsum,
    float* __restrict__ out) {
  int idx = blockIdx.x * 256 + threadIdx.x;
  int row = idx >> 4;
  int h4 = (idx & 15) * 4;
  int b = row >> 11, t = row & 2047;
  int qt = t >> 7, r = t & 127;
  float O0 = 0.f, O1 = 0.f, O2 = 0.f, O3 = 0.f, l = 0.f;
#pragma unroll
  for (int s = 0; s < 4; ++s) {
    size_t p = (((size_t)s * 8 + b) * 16 + qt) * 128 + r;
    l += lsum[p];
    ushort4 ov = *(const ushort4*)&Op[p * 64 + h4];
    O0 += bf2f(ov.x); O1 += bf2f(ov.y); O2 += bf2f(ov.z); O3 += bf2f(ov.w);
  }
  float inv = 1.0f / l;
  float4 res = make_float4(O0 * inv, O1 * inv, O2 * inv, O3 * inv);
  *(float4*)&out[(size_t)row * H_ + h4] = res;
}

extern "C" void kernel_launch(void* const* d_in, const int* in_sizes, int n_in,
                              void* d_out, int out_size, void* d_ws, size_t ws_size,
                              hipStream_t stream) {
  const float* x  = (const float*)d_in[0];
  const float* wq = (const float*)d_in[1];
  const float* wk = (const float*)d_in[2];
  const float* wv = (const float*)d_in[3];
  float* out = (float*)d_out;

  char* ws = (char*)d_ws;
  unsigned short* wf = (unsigned short*)ws;                    // 393216 B
  unsigned short* qb = (unsigned short*)(ws + 393216);         // 2097152 B
  unsigned short* kf = (unsigned short*)(ws + 2490368);        // 2097152 B (frag-ready)
  unsigned short* vf = (unsigned short*)(ws + 4587520);        // 2097152 B (frag-ready)
  unsigned short* Op = (unsigned short*)(ws + 6684672);        // 8388608 B (4 splits)
  float*          ls = (float*)(ws + 15073280);                // 262144 B (total 15335424)

  conv_w<<<96, 256, 0, stream>>>(wq, wk, wv, wf);
  qkv_proj<<<512, 256, 0, stream>>>(x, wf, qb, kf, vf);
  attn<<<dim3(16, 8, 4), 512, 0, stream>>>(qb, kf, vf, Op, ls);
  merge_splits<<<1024, 256, 0, stream>>>(Op, ls, out);
}